// Round 1
// baseline (77264.056 us; speedup 1.0000x reference)
//
#include <hip/hip_runtime.h>

#define B 64
#define T 256
#define H 512
#define G4 2048     // 4*H
#define D0 128
#define NL 6

#define NBLK 256
#define NTHR 256
#define KT 64

// ---------------------------------------------------------------------------
// Per-layer persistent LSTM kernel.
// Grid: 256 blocks x 256 threads (1 block/CU -> co-resident, safe spin barrier).
// Block `blk` owns hidden columns {2*blk, 2*blk+1}; wave w (=gate g) computes
// gate rows g*512 + {2*blk, 2*blk+1}. Lane index = batch b (B==64==wavefront).
// W rows are wave-uniform -> scalar loads; h/x tiles staged in LDS.
// ---------------------------------------------------------------------------

__device__ __forceinline__ void gemm_tiles(
    const float* __restrict__ src, int srstride,
    const float* __restrict__ WA, const float* __restrict__ WB,
    int Kdim, float (*x_s)[KT + 4], int tid, int lane,
    float& accA, float& accB)
{
  for (int k0 = 0; k0 < Kdim; k0 += KT) {
    // cooperative stage: 64 rows x 64 floats, coalesced float4 loads
#pragma unroll
    for (int i = 0; i < 4; ++i) {
      int f = tid + NTHR * i;          // float4 id, 0..1023
      int r = f >> 4;                  // row 0..63 (= batch)
      int c4 = (f & 15) << 2;          // float offset 0..60
      *(float4*)&x_s[r][c4] =
          *(const float4*)(src + (size_t)r * srstride + k0 + c4);
    }
    __syncthreads();
#pragma unroll
    for (int kk = 0; kk < KT; kk += 4) {
      float4 hv = *(const float4*)&x_s[lane][kk];
      float4 wa = *(const float4*)(WA + k0 + kk);   // wave-uniform -> s_load
      float4 wb = *(const float4*)(WB + k0 + kk);
      accA = fmaf(hv.x, wa.x, accA); accB = fmaf(hv.x, wb.x, accB);
      accA = fmaf(hv.y, wa.y, accA); accB = fmaf(hv.y, wb.y, accB);
      accA = fmaf(hv.z, wa.z, accA); accB = fmaf(hv.z, wb.z, accB);
      accA = fmaf(hv.w, wa.w, accA); accB = fmaf(hv.w, wb.w, accB);
    }
    __syncthreads();
  }
}

__global__ void __launch_bounds__(NTHR) lstm_layer(
    const float* __restrict__ xin, int Din,
    const float* __restrict__ Wih, const float* __restrict__ Whh,
    const float* __restrict__ bih, const float* __restrict__ bhh,
    float* __restrict__ yout,
    unsigned* __restrict__ bar)
{
  __shared__ float x_s[64][KT + 4];
  __shared__ float g_s[8][64];

  const int tid  = threadIdx.x;
  const int lane = tid & 63;          // batch index
  const int wv   = tid >> 6;          // 0..3 = gate (i,f,g,o)
  const int blk  = blockIdx.x;
  const int j0   = blk * 2;           // owned hidden cols: j0, j0+1

  const int rAu = __builtin_amdgcn_readfirstlane(wv * H + j0);
  const int rBu = rAu + 1;
  const float biasA = bih[rAu] + bhh[rAu];
  const float biasB = bih[rBu] + bhh[rBu];
  const float* WihA = Wih + (size_t)rAu * Din;
  const float* WihB = Wih + (size_t)rBu * Din;
  const float* WhhA = Whh + (size_t)rAu * H;
  const float* WhhB = Whh + (size_t)rBu * H;

  // pointwise ownership (tid < 128): b = tid>>1, j = j0 + (tid&1)
  const int pb = tid >> 1, pj = tid & 1;
  float creg = 0.f;

  unsigned* cnt = bar;
  unsigned* gen = bar + 1;

  for (int t = 0; t < T; ++t) {
    float accA = biasA, accB = biasB;

    // ---- input projection part (no dependence on h(t-1): overlaps barrier)
    gemm_tiles(xin + (size_t)t * Din, T * Din, WihA, WihB, Din,
               x_s, tid, lane, accA, accB);

    if (t > 0) {
      // ---- wait: h(t-1) published by all blocks
      if (tid == 0) {
        while ((int)(__hip_atomic_load(gen, __ATOMIC_RELAXED,
                                       __HIP_MEMORY_SCOPE_AGENT) -
                     (unsigned)t) < 0)
          __builtin_amdgcn_s_sleep(2);
        __threadfence();   // acquire: invalidate caches before h reads
      }
      __syncthreads();
      // ---- recurrent part
      gemm_tiles(yout + (size_t)(t - 1) * H, T * H, WhhA, WhhB, H,
                 x_s, tid, lane, accA, accB);
    }

    // ---- gates to LDS, block-local pointwise
    g_s[wv * 2 + 0][lane] = accA;
    g_s[wv * 2 + 1][lane] = accB;
    __syncthreads();
    if (tid < 128) {
      float gi = g_s[0 + pj][pb];
      float gf = g_s[2 + pj][pb];
      float gg = g_s[4 + pj][pb];
      float go = g_s[6 + pj][pb];
      float iv = 1.f / (1.f + expf(-gi));
      float fv = 1.f / (1.f + expf(-gf));
      float gv = tanhf(gg);
      float ov = 1.f / (1.f + expf(-go));
      creg = fv * creg + iv * gv;
      float hv = ov * tanhf(creg);
      yout[(size_t)pb * (T * H) + (size_t)t * H + j0 + pj] = hv;
    }

    // ---- arrive (release h(t) writes); no closing sync needed
    __syncthreads();   // drains this block's stores, finishes g_s reads
    if (tid == 0) {
      __threadfence(); // release: write back L2 so other XCDs see h(t)
      unsigned arr = __hip_atomic_fetch_add(cnt, 1u, __ATOMIC_ACQ_REL,
                                            __HIP_MEMORY_SCOPE_AGENT) + 1u;
      if (arr == NBLK) {
        __hip_atomic_store(cnt, 0u, __ATOMIC_RELAXED,
                           __HIP_MEMORY_SCOPE_AGENT);
        __hip_atomic_fetch_add(gen, 1u, __ATOMIC_RELEASE,
                               __HIP_MEMORY_SCOPE_AGENT);
      }
    }
  }
}

// ---------------------------------------------------------------------------
// Final FC on last timestep: out[b][o] = y[b][T-1][:] . fc_w[o][:] + fc_b[o]
// ---------------------------------------------------------------------------
__global__ void __launch_bounds__(640) fc_kernel(
    const float* __restrict__ y, const float* __restrict__ w,
    const float* __restrict__ bias, float* __restrict__ out)
{
  int tid = threadIdx.x;
  if (tid >= 640) return;
  int b = tid / 10, o = tid - b * 10;
  const float* yr = y + (size_t)b * (T * H) + (size_t)(T - 1) * H;
  const float* wr = w + (size_t)o * H;
  float acc = bias[o];
  for (int k = 0; k < H; ++k) acc = fmaf(yr[k], wr[k], acc);
  out[b * 10 + o] = acc;
}

extern "C" void kernel_launch(void* const* d_in, const int* in_sizes, int n_in,
                              void* d_out, int out_size, void* d_ws,
                              size_t ws_size, hipStream_t stream)
{
  const float* x    = (const float*)d_in[0];
  const float* Wih0 = (const float*)d_in[1];
  const float* WihR = (const float*)d_in[2];
  const float* Whh  = (const float*)d_in[3];
  const float* bih  = (const float*)d_in[4];
  const float* bhh  = (const float*)d_in[5];
  const float* fcw  = (const float*)d_in[6];
  const float* fcb  = (const float*)d_in[7];
  float* out = (float*)d_out;

  // ws layout: [0,256): barrier {count, gen}; then two [B,T,H] f32 ping-pong
  unsigned* bar = (unsigned*)d_ws;
  float* y0 = (float*)((char*)d_ws + 256);
  float* y1 = y0 + (size_t)B * T * H;

  const float* cur = x;
  int Din = D0;
  for (int l = 0; l < NL; ++l) {
    hipMemsetAsync(d_ws, 0, 256, stream);   // reset barrier for this layer
    const float* Wih_l = (l == 0) ? Wih0 : (WihR + (size_t)(l - 1) * G4 * H);
    const float* Whh_l = Whh + (size_t)l * G4 * H;
    float* yo = (l & 1) ? y1 : y0;
    lstm_layer<<<NBLK, NTHR, 0, stream>>>(cur, Din, Wih_l, Whh_l,
                                          bih + l * G4, bhh + l * G4, yo, bar);
    cur = yo;
    Din = H;
  }
  fc_kernel<<<1, 640, 0, stream>>>(cur, fcw, fcb, out);
}

// Round 4
// 77060.596 us; speedup vs baseline: 1.0026x; 1.0026x over previous
//
#include <hip/hip_runtime.h>

#define B 64
#define T 256
#define H 512
#define G4 2048     // 4*H
#define D0 128
#define NL 6
#define TC 64       // timestep chunk
#define NCHUNK (T / TC)
#define NBLK 256

// ===========================================================================
// xp_gemm: xp[s][r][b] = sum_k x[b][t0+s][k] * Wih[r][k] + bih[r] + bhh[r]
// (xp is indexed by CHUNK-LOCAL s — round-1/2 bug was absolute-t indexing,
//  which ran 3 chunks past the 32 MiB xpb straight into the y buffer.)
// grid = TC*4 blocks (t, 512-row tile); 512 threads = 8 waves; lane = batch.
// Accumulation order: bias first, then k ascending — matches round-0 chain.
// ===========================================================================
__global__ void __launch_bounds__(512) xp_gemm(
    const float* __restrict__ x, int Din, int dqs,
    const float* __restrict__ Wih,
    const float* __restrict__ bih, const float* __restrict__ bhh,
    float* __restrict__ xp, int t0)
{
  __shared__ float x_s[64 * 129 * 4];
  const int tid  = threadIdx.x;
  const int lane = tid & 63;
  const int w    = __builtin_amdgcn_readfirstlane(tid >> 6);
  const int s    = (int)blockIdx.x >> 2;      // chunk-local step
  const int t    = t0 + s;                    // absolute step (for x read)
  const int rt   = ((int)blockIdx.x & 3) * 512;
  const int Dq   = Din >> 2;            // float4 units per row (32 or 128)
  const int su   = Dq + 1;              // padded stride (odd)

  const int nf4 = 64 * Dq;
  for (int f = tid; f < nf4; f += 512) {
    int b = f >> dqs;
    int u = f & (Dq - 1);
    float4 v = *(const float4*)(x + ((size_t)b * T + t) * Din + u * 4);
    *(float4*)&x_s[(b * su + u) * 4] = v;
  }
  __syncthreads();

  const float* xrow = &x_s[lane * su * 4];
  for (int grp = 0; grp < 8; ++grp) {
    const int r0 = rt + w * 64 + grp * 8;  // wave-uniform row base
    float acc[8];
#pragma unroll
    for (int rr = 0; rr < 8; ++rr) acc[rr] = bih[r0 + rr] + bhh[r0 + rr];
#pragma unroll 4
    for (int q = 0; q < Dq; ++q) {
      float4 hv = *(const float4*)(xrow + q * 4);
#pragma unroll
      for (int rr = 0; rr < 8; ++rr) {
        float4 wv = *(const float4*)(Wih + (size_t)(r0 + rr) * Din + q * 4);
        acc[rr] = fmaf(hv.w, wv.w,
                  fmaf(hv.z, wv.z, fmaf(hv.y, wv.y, fmaf(hv.x, wv.x, acc[rr]))));
      }
    }
    float* op = xp + ((size_t)s * G4 + r0) * 64 + lane;   // chunk-local s
#pragma unroll
    for (int rr = 0; rr < 8; ++rr) op[rr * 64] = acc[rr];
  }
}

// ===========================================================================
// lstm_rec: round-0-proven skeleton. 256 blocks x 256 threads; wave = gate,
// 2 rows/wave, lane = batch; h(t-1) staged in ONE LDS phase per step.
// xp read is indexed by chunk-local s (the fix).
// ===========================================================================
__global__ void __launch_bounds__(256) lstm_rec(
    const float* __restrict__ xp, const float* __restrict__ Whh,
    float* __restrict__ y, float* __restrict__ cbuf,
    int t0, unsigned* __restrict__ bar)
{
  __shared__ float h_s[64 * 129 * 4];   // 132096 B, odd float4 stride
  __shared__ float g_s[8][64];

  const int tid  = threadIdx.x;
  const int lane = tid & 63;            // batch
  const int wv   = tid >> 6;            // 0..3 = gate (i,f,g,o)
  const int j0   = (int)blockIdx.x * 2; // owned hidden cols j0, j0+1

  const int rAu = __builtin_amdgcn_readfirstlane(wv * H + j0);
  const int rBu = rAu + 1;
  const float* WA = Whh + (size_t)rAu * H;
  const float* WB = Whh + (size_t)rBu * H;

  const int pb = tid >> 1, pj = tid & 1;
  float creg = 0.f;
  if (t0 > 0 && tid < 128) creg = cbuf[pb * H + j0 + pj];

  unsigned* cnt = bar;
  unsigned* gen = bar + 1;

  for (int s = 0; s < TC; ++s) {
    const int t = t0 + s;
    // chunk-local xp index (THE round-3 fix)
    float accA = xp[((size_t)s * G4 + rAu) * 64 + lane];
    float accB = xp[((size_t)s * G4 + rBu) * 64 + lane];

    if (t > 0) {
      if (s > 0) {   // h(t-1) from the previous launch needs no wait
        if (tid == 0) {
          while ((int)(__hip_atomic_load(gen, __ATOMIC_RELAXED,
                                         __HIP_MEMORY_SCOPE_AGENT) -
                       (unsigned)s) < 0)
            __builtin_amdgcn_s_sleep(2);
          __threadfence();   // acquire
        }
        __syncthreads();
      }
      // stage h(t-1): 128KB, coalesced 16B loads, conflict-free LDS layout
      for (int f = tid; f < 64 * 128; f += 256) {
        int b = f >> 7, u = f & 127;
        float4 v = *(const float4*)(y + ((size_t)b * T + (t - 1)) * H + u * 4);
        *(float4*)&h_s[(b * 129 + u) * 4] = v;
      }
      __syncthreads();
      // full-K fma chain per row, k ascending — round-0's exact order
      const float* hrow = &h_s[lane * 129 * 4];
#pragma unroll 8
      for (int q = 0; q < 128; ++q) {
        float4 hv = *(const float4*)(hrow + q * 4);
        float4 wa = *(const float4*)(WA + q * 4);   // wave-uniform -> s_load
        float4 wb = *(const float4*)(WB + q * 4);
        accA = fmaf(hv.x, wa.x, accA); accB = fmaf(hv.x, wb.x, accB);
        accA = fmaf(hv.y, wa.y, accA); accB = fmaf(hv.y, wb.y, accB);
        accA = fmaf(hv.z, wa.z, accA); accB = fmaf(hv.z, wb.z, accB);
        accA = fmaf(hv.w, wa.w, accA); accB = fmaf(hv.w, wb.w, accB);
      }
    }

    // ---- gates to LDS, block-local pointwise (round-0 verbatim)
    g_s[wv * 2 + 0][lane] = accA;
    g_s[wv * 2 + 1][lane] = accB;
    __syncthreads();
    if (tid < 128) {
      float gi = g_s[0 + pj][pb];
      float gf = g_s[2 + pj][pb];
      float gg = g_s[4 + pj][pb];
      float go = g_s[6 + pj][pb];
      float iv = 1.f / (1.f + expf(-gi));
      float fv = 1.f / (1.f + expf(-gf));
      float gv = tanhf(gg);
      float ov = 1.f / (1.f + expf(-go));
      creg = fv * creg + iv * gv;
      float hv = ov * tanhf(creg);
      y[((size_t)pb * T + t) * H + j0 + pj] = hv;
    }

    // ---- arrive (round-0 verbatim)
    __syncthreads();   // drains h stores, finishes g_s reads
    if (tid == 0) {
      __threadfence(); // release
      unsigned arr = __hip_atomic_fetch_add(cnt, 1u, __ATOMIC_ACQ_REL,
                                            __HIP_MEMORY_SCOPE_AGENT) + 1u;
      if (arr == NBLK) {
        __hip_atomic_store(cnt, 0u, __ATOMIC_RELAXED,
                           __HIP_MEMORY_SCOPE_AGENT);
        __hip_atomic_fetch_add(gen, 1u, __ATOMIC_RELEASE,
                               __HIP_MEMORY_SCOPE_AGENT);
      }
    }
  }
  if (tid < 128) cbuf[pb * H + j0 + pj] = creg;
}

// ===========================================================================
// Final FC on last timestep.
// ===========================================================================
__global__ void __launch_bounds__(640) fc_kernel(
    const float* __restrict__ y, const float* __restrict__ w,
    const float* __restrict__ bias, float* __restrict__ out)
{
  int tid = threadIdx.x;
  if (tid >= 640) return;
  int b = tid / 10, o = tid - b * 10;
  const float* yr = y + (size_t)b * (T * H) + (size_t)(T - 1) * H;
  const float* wr = w + (size_t)o * H;
  float acc = bias[o];
  for (int k = 0; k < H; ++k) acc = fmaf(yr[k], wr[k], acc);
  out[b * 10 + o] = acc;
}

extern "C" void kernel_launch(void* const* d_in, const int* in_sizes, int n_in,
                              void* d_out, int out_size, void* d_ws,
                              size_t ws_size, hipStream_t stream)
{
  const float* x    = (const float*)d_in[0];
  const float* Wih0 = (const float*)d_in[1];
  const float* WihR = (const float*)d_in[2];
  const float* Whh  = (const float*)d_in[3];
  const float* bih  = (const float*)d_in[4];
  const float* bhh  = (const float*)d_in[5];
  const float* fcw  = (const float*)d_in[6];
  const float* fcb  = (const float*)d_in[7];
  float* out = (float*)d_out;

  // ws: [0,256) barrier {cnt, gen}; cbuf [B][H]; xp chunk [TC][G4][B]; y [B][T][H]
  unsigned* bar = (unsigned*)d_ws;
  float* cbuf = (float*)((char*)d_ws + 256);
  float* xpb  = (float*)((char*)d_ws + 256 + (size_t)B * H * 4);
  float* y    = xpb + (size_t)TC * G4 * B;

  const float* cur = x;
  int Din = D0, dqs = 5;
  for (int l = 0; l < NL; ++l) {
    const float* Wih_l = (l == 0) ? Wih0 : (WihR + (size_t)(l - 1) * G4 * H);
    const float* Whh_l = Whh + (size_t)l * G4 * H;
    for (int c = 0; c < NCHUNK; ++c) {
      int t0 = c * TC;
      xp_gemm<<<TC * 4, 512, 0, stream>>>(cur, Din, dqs, Wih_l,
                                          bih + l * G4, bhh + l * G4, xpb, t0);
      hipMemsetAsync(bar, 0, 8, stream);  // fresh barrier -> round-0 wait logic
      lstm_rec<<<NBLK, 256, 0, stream>>>(xpb, Whh_l, y, cbuf, t0, bar);
    }
    cur = y; Din = H; dqs = 7;
  }
  fc_kernel<<<1, 640, 0, stream>>>(y, fcw, fcb, out);
}

// Round 5
// 39341.962 us; speedup vs baseline: 1.9639x; 1.9587x over previous
//
#include <hip/hip_runtime.h>

#define B 64
#define T 256
#define H 512
#define G4 2048     // 4*H
#define D0 128
#define NL 6
#define TC 64       // timestep chunk
#define NCHUNK (T / TC)
#define NBLK 256

// ===========================================================================
// xp_gemm: xp[s][r][b] = sum_k x[b][t0+s][k] * Wih[r][k] + bih[r] + bhh[r]
// (unchanged from round 3 — proven)
// ===========================================================================
__global__ void __launch_bounds__(512) xp_gemm(
    const float* __restrict__ x, int Din, int dqs,
    const float* __restrict__ Wih,
    const float* __restrict__ bih, const float* __restrict__ bhh,
    float* __restrict__ xp, int t0)
{
  __shared__ float x_s[64 * 129 * 4];
  const int tid  = threadIdx.x;
  const int lane = tid & 63;
  const int w    = __builtin_amdgcn_readfirstlane(tid >> 6);
  const int s    = (int)blockIdx.x >> 2;      // chunk-local step
  const int t    = t0 + s;                    // absolute step (for x read)
  const int rt   = ((int)blockIdx.x & 3) * 512;
  const int Dq   = Din >> 2;            // float4 units per row (32 or 128)
  const int su   = Dq + 1;              // padded stride (odd)

  const int nf4 = 64 * Dq;
  for (int f = tid; f < nf4; f += 512) {
    int b = f >> dqs;
    int u = f & (Dq - 1);
    float4 v = *(const float4*)(x + ((size_t)b * T + t) * Din + u * 4);
    *(float4*)&x_s[(b * su + u) * 4] = v;
  }
  __syncthreads();

  const float* xrow = &x_s[lane * su * 4];
  for (int grp = 0; grp < 8; ++grp) {
    const int r0 = rt + w * 64 + grp * 8;  // wave-uniform row base
    float acc[8];
#pragma unroll
    for (int rr = 0; rr < 8; ++rr) acc[rr] = bih[r0 + rr] + bhh[r0 + rr];
#pragma unroll 4
    for (int q = 0; q < Dq; ++q) {
      float4 hv = *(const float4*)(xrow + q * 4);
#pragma unroll
      for (int rr = 0; rr < 8; ++rr) {
        float4 wv = *(const float4*)(Wih + (size_t)(r0 + rr) * Din + q * 4);
        acc[rr] = fmaf(hv.w, wv.w,
                  fmaf(hv.z, wv.z, fmaf(hv.y, wv.y, fmaf(hv.x, wv.x, acc[rr]))));
      }
    }
    float* op = xp + ((size_t)s * G4 + r0) * 64 + lane;   // chunk-local s
#pragma unroll
    for (int rr = 0; rr < 8; ++rr) op[rr * 64] = acc[rr];
  }
}

// ===========================================================================
// lstm_rec — round-4 deltas (fence elimination):
//  (1) NO __threadfence anywhere: the round-3 hot loop's agent-scope fences
//      emit L2 writeback/invalidate on gfx950 (non-coherent XCD L2s), nuking
//      the L2-resident W_hh 256x per step -> the measured 43us/step stall.
//  (2) h(t) published with agent-scope RELAXED atomic stores (sc1
//      write-through to the coherence point). Readers use plain float4
//      loads: h lines for step t are first-touch per XCD within this kernel
//      (addresses move with t), so no stale L1/L2 copy can exist.
//  (3) Barrier: monotonic arrive counter (never reset -> no reset/publish
//      ordering hazard), all atomics RELAXED at AGENT scope; ISA ordering
//      comes from __syncthreads' vmcnt(0) drain before the arrive.
//  (4) 4 independent fma chains per gate row (dep depth 512 -> 128);
//      f32 reorder noise ~1e-6, far below the 8.3e-4 threshold.
// ===========================================================================
__global__ void __launch_bounds__(256) lstm_rec(
    const float* __restrict__ xp, const float* __restrict__ Whh,
    float* __restrict__ y, float* __restrict__ cbuf,
    int t0, unsigned* __restrict__ bar)
{
  __shared__ float h_s[64 * 129 * 4];   // 132096 B, odd float4 stride
  __shared__ float g_s[8][64];

  const int tid  = threadIdx.x;
  const int lane = tid & 63;            // batch
  const int wv   = tid >> 6;            // 0..3 = gate (i,f,g,o)
  const int j0   = (int)blockIdx.x * 2; // owned hidden cols j0, j0+1

  const int rAu = __builtin_amdgcn_readfirstlane(wv * H + j0);
  const int rBu = rAu + 1;
  const float* WA = Whh + (size_t)rAu * H;
  const float* WB = Whh + (size_t)rBu * H;

  const int pb = tid >> 1, pj = tid & 1;
  float creg = 0.f;
  if (t0 > 0 && tid < 128) creg = cbuf[pb * H + j0 + pj];

  unsigned* cnt = bar;
  unsigned* gen = bar + 1;

  for (int s = 0; s < TC; ++s) {
    const int t = t0 + s;
    float xpA = xp[((size_t)s * G4 + rAu) * 64 + lane];
    float xpB = xp[((size_t)s * G4 + rBu) * 64 + lane];
    // 4 independent partial chains per row (x,y,z,w components)
    float a0 = xpA, a1 = 0.f, a2 = 0.f, a3 = 0.f;
    float b0 = xpB, b1 = 0.f, b2 = 0.f, b3 = 0.f;

    if (t > 0) {
      if (s > 0) {   // h(t-1) from the previous launch needs no wait
        if (tid == 0) {
          while ((int)(__hip_atomic_load(gen, __ATOMIC_RELAXED,
                                         __HIP_MEMORY_SCOPE_AGENT) -
                       (unsigned)s) < 0)
            __builtin_amdgcn_s_sleep(2);
        }
        __syncthreads();
      }
      // stage h(t-1): 128KB, coalesced 16B loads, conflict-free LDS layout.
      // Plain loads are coherent here: first touch of these lines by this
      // XCD inside this kernel; writers pushed them to L3 via sc1 stores.
      for (int f = tid; f < 64 * 128; f += 256) {
        int b = f >> 7, u = f & 127;
        float4 v = *(const float4*)(y + ((size_t)b * T + (t - 1)) * H + u * 4);
        *(float4*)&h_s[(b * 129 + u) * 4] = v;
      }
      __syncthreads();
      const float* hrow = &h_s[lane * 129 * 4];
#pragma unroll 8
      for (int q = 0; q < 128; ++q) {
        float4 hv = *(const float4*)(hrow + q * 4);
        float4 wa = *(const float4*)(WA + q * 4);   // wave-uniform -> s_load
        float4 wb = *(const float4*)(WB + q * 4);
        a0 = fmaf(hv.x, wa.x, a0); b0 = fmaf(hv.x, wb.x, b0);
        a1 = fmaf(hv.y, wa.y, a1); b1 = fmaf(hv.y, wb.y, b1);
        a2 = fmaf(hv.z, wa.z, a2); b2 = fmaf(hv.z, wb.z, b2);
        a3 = fmaf(hv.w, wa.w, a3); b3 = fmaf(hv.w, wb.w, b3);
      }
    }
    float accA = (a0 + a1) + (a2 + a3);
    float accB = (b0 + b1) + (b2 + b3);

    // ---- gates to LDS, block-local pointwise
    g_s[wv * 2 + 0][lane] = accA;
    g_s[wv * 2 + 1][lane] = accB;
    __syncthreads();
    if (tid < 128) {
      float gi = g_s[0 + pj][pb];
      float gf = g_s[2 + pj][pb];
      float gg = g_s[4 + pj][pb];
      float go = g_s[6 + pj][pb];
      float iv = 1.f / (1.f + expf(-gi));
      float fv = 1.f / (1.f + expf(-gf));
      float gv = tanhf(gg);
      float ov = 1.f / (1.f + expf(-go));
      creg = fv * creg + iv * gv;
      float hv = ov * tanhf(creg);
      // publish h(t) at the coherence point (sc1 write-through), no fence
      __hip_atomic_store(&y[((size_t)pb * T + t) * H + j0 + pj], hv,
                         __ATOMIC_RELAXED, __HIP_MEMORY_SCOPE_AGENT);
    }

    // ---- arrive: monotonic counter, all relaxed; __syncthreads drains
    //      vmcnt(0) so every h-store is at L3 before our arrival is visible
    __syncthreads();
    if (tid == 0) {
      unsigned arr = __hip_atomic_fetch_add(cnt, 1u, __ATOMIC_RELAXED,
                                            __HIP_MEMORY_SCOPE_AGENT) + 1u;
      if (arr == (unsigned)((s + 1) * NBLK)) {
        __hip_atomic_fetch_add(gen, 1u, __ATOMIC_RELAXED,
                               __HIP_MEMORY_SCOPE_AGENT);
      }
    }
  }
  if (tid < 128) cbuf[pb * H + j0 + pj] = creg;
}

// ===========================================================================
// Final FC on last timestep.
// ===========================================================================
__global__ void __launch_bounds__(640) fc_kernel(
    const float* __restrict__ y, const float* __restrict__ w,
    const float* __restrict__ bias, float* __restrict__ out)
{
  int tid = threadIdx.x;
  if (tid >= 640) return;
  int b = tid / 10, o = tid - b * 10;
  const float* yr = y + (size_t)b * (T * H) + (size_t)(T - 1) * H;
  const float* wr = w + (size_t)o * H;
  float acc = bias[o];
  for (int k = 0; k < H; ++k) acc = fmaf(yr[k], wr[k], acc);
  out[b * 10 + o] = acc;
}

extern "C" void kernel_launch(void* const* d_in, const int* in_sizes, int n_in,
                              void* d_out, int out_size, void* d_ws,
                              size_t ws_size, hipStream_t stream)
{
  const float* x    = (const float*)d_in[0];
  const float* Wih0 = (const float*)d_in[1];
  const float* WihR = (const float*)d_in[2];
  const float* Whh  = (const float*)d_in[3];
  const float* bih  = (const float*)d_in[4];
  const float* bhh  = (const float*)d_in[5];
  const float* fcw  = (const float*)d_in[6];
  const float* fcb  = (const float*)d_in[7];
  float* out = (float*)d_out;

  // ws: [0,256) barrier {cnt, gen}; cbuf [B][H]; xp chunk [TC][G4][B]; y [B][T][H]
  unsigned* bar = (unsigned*)d_ws;
  float* cbuf = (float*)((char*)d_ws + 256);
  float* xpb  = (float*)((char*)d_ws + 256 + (size_t)B * H * 4);
  float* y    = xpb + (size_t)TC * G4 * B;

  const float* cur = x;
  int Din = D0, dqs = 5;
  for (int l = 0; l < NL; ++l) {
    const float* Wih_l = (l == 0) ? Wih0 : (WihR + (size_t)(l - 1) * G4 * H);
    const float* Whh_l = Whh + (size_t)l * G4 * H;
    for (int c = 0; c < NCHUNK; ++c) {
      int t0 = c * TC;
      xp_gemm<<<TC * 4, 512, 0, stream>>>(cur, Din, dqs, Wih_l,
                                          bih + l * G4, bhh + l * G4, xpb, t0);
      hipMemsetAsync(bar, 0, 8, stream);  // fresh {cnt, gen} per chunk
      lstm_rec<<<NBLK, 256, 0, stream>>>(xpb, Whh_l, y, cbuf, t0, bar);
    }
    cur = y; Din = H; dqs = 7;
  }
  fc_kernel<<<1, 640, 0, stream>>>(y, fcw, fcb, out);
}

// Round 6
// 21267.943 us; speedup vs baseline: 3.6329x; 1.8498x over previous
//
#include <hip/hip_runtime.h>

#define B 64
#define T 256
#define H 512
#define G4 2048     // 4*H
#define D0 128
#define NL 6
#define TC 64       // timestep chunk
#define NCHUNK (T / TC)

#define NBLK_R 128  // recurrence blocks (4 hidden cols each)
#define FSTRIDE 16  // u32 stride between per-block flags (64B lines)

// ===========================================================================
// xp_gemm: xp[s][r][b] = sum_k x[b][t0+s][k] * Wih[r][k] + bih[r] + bhh[r]
// (unchanged — proven in rounds 3-5)
// ===========================================================================
__global__ void __launch_bounds__(512) xp_gemm(
    const float* __restrict__ x, int Din, int dqs,
    const float* __restrict__ Wih,
    const float* __restrict__ bih, const float* __restrict__ bhh,
    float* __restrict__ xp, int t0)
{
  __shared__ float x_s[64 * 129 * 4];
  const int tid  = threadIdx.x;
  const int lane = tid & 63;
  const int w    = __builtin_amdgcn_readfirstlane(tid >> 6);
  const int s    = (int)blockIdx.x >> 2;
  const int t    = t0 + s;
  const int rt   = ((int)blockIdx.x & 3) * 512;
  const int Dq   = Din >> 2;
  const int su   = Dq + 1;

  const int nf4 = 64 * Dq;
  for (int f = tid; f < nf4; f += 512) {
    int b = f >> dqs;
    int u = f & (Dq - 1);
    float4 v = *(const float4*)(x + ((size_t)b * T + t) * Din + u * 4);
    *(float4*)&x_s[(b * su + u) * 4] = v;
  }
  __syncthreads();

  const float* xrow = &x_s[lane * su * 4];
  for (int grp = 0; grp < 8; ++grp) {
    const int r0 = rt + w * 64 + grp * 8;
    float acc[8];
#pragma unroll
    for (int rr = 0; rr < 8; ++rr) acc[rr] = bih[r0 + rr] + bhh[r0 + rr];
#pragma unroll 4
    for (int q = 0; q < Dq; ++q) {
      float4 hv = *(const float4*)(xrow + q * 4);
#pragma unroll
      for (int rr = 0; rr < 8; ++rr) {
        float4 wv = *(const float4*)(Wih + (size_t)(r0 + rr) * Din + q * 4);
        acc[rr] = fmaf(hv.w, wv.w,
                  fmaf(hv.z, wv.z, fmaf(hv.y, wv.y, fmaf(hv.x, wv.x, acc[rr]))));
      }
    }
    float* op = xp + ((size_t)s * G4 + r0) * 64 + lane;
#pragma unroll
    for (int rr = 0; rr < 8; ++rr) op[rr * 64] = acc[rr];
  }
}

// ===========================================================================
// lstm_rec — round-5 restructure (targets the 19.5us/step residual stall):
//  (1) 128 blocks x 1024 threads: 16 waves/CU (4/SIMD) -> TLP hides
//      stage-load + s_load latency (round-5 had 1 wave/SIMD, zero hiding).
//  (2) Flag-ARRAY barrier: round-5 arrived via 256 serialized atomicAdds on
//      ONE line at the coherence point (~10us/step of contention). Now each
//      block stores its own 64B-padded flag (monotonic global-step value,
//      no reset, no contention); waiters poll the 128 flags directly.
//  (3) Publish: 4 consecutive threads write 16B-contiguous y[b][t][j0..j0+3]
//      (was 8B over 256 blocks), still agent-scope sc1 write-through.
//  Per-gate-row accumulation chain (xp init + k-ascending 4 chains) is
//  bit-identical to round-5 -> absmax 0.0 expected.
// ===========================================================================
__global__ void __launch_bounds__(1024, 4) lstm_rec(
    const float* __restrict__ xp, const float* __restrict__ Whh,
    float* __restrict__ y, float* __restrict__ cbuf,
    int t0, unsigned gbase, unsigned* __restrict__ flags)
{
  __shared__ float h_s[64 * 129 * 4];   // 132096 B, odd float4 stride
  __shared__ float g_s[16][64];         // [gate*4+col][batch]

  const int tid  = threadIdx.x;
  const int lane = tid & 63;            // batch
  const int w    = tid >> 6;            // wave 0..15
  const int wl   = __builtin_amdgcn_readfirstlane(w);
  const int blk  = (int)blockIdx.x;
  const int j0   = blk * 4;             // owned hidden cols j0..j0+3

  // wave wl computes gate row: gate = wl>>2, col = j0 + (wl&3)
  const int grow = (wl >> 2) * H + j0 + (wl & 3);
  const float* W = Whh + (size_t)grow * H;

  // pointwise ownership (tid < 256): b = tid>>2, j = j0 + (tid&3)
  const int pb = tid >> 2, pcj = tid & 3;
  float creg = 0.f;
  if (t0 > 0 && tid < 256) creg = cbuf[pb * H + j0 + pcj];

  for (int s = 0; s < TC; ++s) {
    const int t = t0 + s;
    // acc chains: xp first, then k ascending (x,y,z,w) — proven order
    float a0 = xp[((size_t)s * G4 + grow) * 64 + lane];
    float a1 = 0.f, a2 = 0.f, a3 = 0.f;

    if (t > 0) {
      if (s > 0) {   // h(t-1) from a previous launch needs no wait
        if (tid < NBLK_R) {
          const unsigned tgt = gbase + (unsigned)s;
          while ((int)(__hip_atomic_load(&flags[tid * FSTRIDE],
                                         __ATOMIC_RELAXED,
                                         __HIP_MEMORY_SCOPE_AGENT) - tgt) < 0)
            __builtin_amdgcn_s_sleep(1);
        }
        __syncthreads();
      }
      // stage h(t-1): 128KB, 8 coalesced float4 loads/thread
#pragma unroll
      for (int i = 0; i < 8; ++i) {
        int f = tid + 1024 * i;
        int b = f >> 7, u = f & 127;
        float4 v = *(const float4*)(y + ((size_t)b * T + (t - 1)) * H + u * 4);
        *(float4*)&h_s[(b * 129 + u) * 4] = v;
      }
      __syncthreads();
      const float* hrow = &h_s[lane * 129 * 4];
#pragma unroll 8
      for (int q = 0; q < 128; ++q) {
        float4 hv = *(const float4*)(hrow + q * 4);
        float4 wv = *(const float4*)(W + q * 4);    // wave-uniform -> s_load
        a0 = fmaf(hv.x, wv.x, a0);
        a1 = fmaf(hv.y, wv.y, a1);
        a2 = fmaf(hv.z, wv.z, a2);
        a3 = fmaf(hv.w, wv.w, a3);
      }
    }
    g_s[w][lane] = (a0 + a1) + (a2 + a3);
    __syncthreads();

    if (tid < 256) {
      float gi = g_s[ 0 + pcj][pb];
      float gf = g_s[ 4 + pcj][pb];
      float gg = g_s[ 8 + pcj][pb];
      float go = g_s[12 + pcj][pb];
      float iv = 1.f / (1.f + expf(-gi));
      float fv = 1.f / (1.f + expf(-gf));
      float gv = tanhf(gg);
      float ov = 1.f / (1.f + expf(-go));
      creg = fv * creg + iv * gv;
      float hv = ov * tanhf(creg);
      // publish at the coherence point (sc1 write-through), 16B/4 threads
      __hip_atomic_store(&y[((size_t)pb * T + t) * H + j0 + pcj], hv,
                         __ATOMIC_RELAXED, __HIP_MEMORY_SCOPE_AGENT);
    }
    __syncthreads();   // drains publish stores; frees g_s/h_s
    if (tid == 0) {
      __hip_atomic_store(&flags[blk * FSTRIDE], gbase + (unsigned)s + 1u,
                         __ATOMIC_RELAXED, __HIP_MEMORY_SCOPE_AGENT);
    }
  }
  if (tid < 256) cbuf[pb * H + j0 + pcj] = creg;
}

// ===========================================================================
// Final FC on last timestep.
// ===========================================================================
__global__ void __launch_bounds__(640) fc_kernel(
    const float* __restrict__ y, const float* __restrict__ w,
    const float* __restrict__ bias, float* __restrict__ out)
{
  int tid = threadIdx.x;
  if (tid >= 640) return;
  int b = tid / 10, o = tid - b * 10;
  const float* yr = y + (size_t)b * (T * H) + (size_t)(T - 1) * H;
  const float* wr = w + (size_t)o * H;
  float acc = bias[o];
  for (int k = 0; k < H; ++k) acc = fmaf(yr[k], wr[k], acc);
  out[b * 10 + o] = acc;
}

extern "C" void kernel_launch(void* const* d_in, const int* in_sizes, int n_in,
                              void* d_out, int out_size, void* d_ws,
                              size_t ws_size, hipStream_t stream)
{
  const float* x    = (const float*)d_in[0];
  const float* Wih0 = (const float*)d_in[1];
  const float* WihR = (const float*)d_in[2];
  const float* Whh  = (const float*)d_in[3];
  const float* bih  = (const float*)d_in[4];
  const float* bhh  = (const float*)d_in[5];
  const float* fcw  = (const float*)d_in[6];
  const float* fcb  = (const float*)d_in[7];
  float* out = (float*)d_out;

  // ws: [0,16K) flag array (128 x 64B); cbuf [B][H]; xp [TC][G4][B]; y [B][T][H]
  unsigned* flags = (unsigned*)d_ws;
  float* cbuf = (float*)((char*)d_ws + 16384);
  float* xpb  = (float*)((char*)d_ws + 16384 + (size_t)B * H * 4);
  float* y    = xpb + (size_t)TC * G4 * B;

  // one reset per call: flags are monotonic within a call (values = global
  // step index), so replays stay deterministic after this memset
  hipMemsetAsync(d_ws, 0, 16384, stream);

  const float* cur = x;
  int Din = D0, dqs = 5;
  for (int l = 0; l < NL; ++l) {
    const float* Wih_l = (l == 0) ? Wih0 : (WihR + (size_t)(l - 1) * G4 * H);
    const float* Whh_l = Whh + (size_t)l * G4 * H;
    for (int c = 0; c < NCHUNK; ++c) {
      int t0 = c * TC;
      unsigned gbase = (unsigned)((l * NCHUNK + c) * TC);
      xp_gemm<<<TC * 4, 512, 0, stream>>>(cur, Din, dqs, Wih_l,
                                          bih + l * G4, bhh + l * G4, xpb, t0);
      lstm_rec<<<NBLK_R, 1024, 0, stream>>>(xpb, Whh_l, y, cbuf, t0, gbase,
                                            flags);
    }
    cur = y; Din = H; dqs = 7;
  }
  fc_kernel<<<1, 640, 0, stream>>>(y, fcw, fcb, out);
}